// Round 4
// baseline (99.165 us; speedup 1.0000x reference)
//
#include <hip/hip_runtime.h>

// CP_Based: out[b,u] = rsqrt(prod_f (1+X^2)) * sum_r prod_f (k0[r,f,u] + X[b,f]*k1[r,f,u])
// X: [B,32] f32, kernel: [2,10,32,8] f32, out: [B,8] f32
//
// R1-R3 established: K must ride the scalar pipe (VMEM broadcast 2.8x worse, R2),
// and runtime tracks TOTAL scalar-load bytes (~1.4 TB/s device cap: R1 40MB/27.8us,
// R3 40MB/31.2us despite 5x TLP). This round cuts scalar bytes 4x by amortizing
// each K read over NB=4 batch rows per thread.
//
// blockDim=(64,10): wave y owns rank y (2KB of K per wave; 20KB per block = K once).
// Thread (lane,y) processes rows base + i*64 + lane, i=0..3 (coalesced dwordx4 X).
// Rank partials summed via 80KiB LDS (lane-major f32x4 layout -> conflict-free b128);
// wave 0 reduces, applies norm, writes out. Grid=512 blocks = exactly 2/CU resident.

typedef float f32x4 __attribute__((ext_vector_type(4)));

#define F 32
#define RANK 10
#define UNITS 8
#define NB 4
#define ROWS (64 * NB)

__global__ __launch_bounds__(64 * RANK) void cp_based_kernel(
    const float* __restrict__ X,
    const float* __restrict__ K,   // [2,10,32,8] flat
    float* __restrict__ out,
    int B)
{
    __shared__ f32x4 red[RANK][2][NB][64];   // 80 KiB, bank-conflict-free layout

    const int lane = threadIdx.x;                                // 0..63
    const int y = __builtin_amdgcn_readfirstlane(threadIdx.y);   // rank id, forced SGPR
    const long rowbase = (long)blockIdx.x * ROWS;

    const float* k0b = K + y * (F * UNITS);                 // k0[y,f,:]
    const float* k1b = K + RANK * F * UNITS + y * (F * UNITS);  // k1[y,f,:]

    f32x4 p[NB][2];
    float np[NB];
#pragma unroll
    for (int i = 0; i < NB; ++i) {
        p[i][0] = f32x4{1.f, 1.f, 1.f, 1.f};
        p[i][1] = f32x4{1.f, 1.f, 1.f, 1.f};
        np[i] = 1.f;
    }

#pragma unroll
    for (int jc = 0; jc < F / 4; ++jc) {
        // X register window: 4 rows x 4 features
        f32x4 xw[NB];
#pragma unroll
        for (int i = 0; i < NB; ++i)
            xw[i] = *reinterpret_cast<const f32x4*>(
                X + (rowbase + i * 64 + lane) * F + jc * 4);

        // norm product only in the output wave (wave-uniform branch)
        if (y == 0) {
#pragma unroll
            for (int i = 0; i < NB; ++i)
#pragma unroll
                for (int jf = 0; jf < 4; ++jf)
                    np[i] *= __builtin_fmaf(xw[i][jf], xw[i][jf], 1.0f);
        }

#pragma unroll
        for (int jf = 0; jf < 4; ++jf) {
            const int f = jc * 4 + jf;
            // uniform addresses -> s_load; values live in SGPRs (1 SGPR/VALU-op legal:
            // pk_mul(v,s) then pk_add(v,s))
            f32x4 k0a = *reinterpret_cast<const f32x4*>(k0b + f * UNITS);
            f32x4 k0c = *reinterpret_cast<const f32x4*>(k0b + f * UNITS + 4);
            f32x4 k1a = *reinterpret_cast<const f32x4*>(k1b + f * UNITS);
            f32x4 k1c = *reinterpret_cast<const f32x4*>(k1b + f * UNITS + 4);
#pragma unroll
            for (int i = 0; i < NB; ++i) {
                float x = xw[i][jf];
                f32x4 xs = {x, x, x, x};
                p[i][0] *= xs * k1a + k0a;
                p[i][1] *= xs * k1c + k0c;
            }
        }
    }

    // stage per-rank products: lane-major f32x4 -> ds_write_b128, banks 0..31 covered
#pragma unroll
    for (int i = 0; i < NB; ++i) {
        red[y][0][i][lane] = p[i][0];
        red[y][1][i][lane] = p[i][1];
    }
    __syncthreads();

    if (y == 0) {
#pragma unroll
        for (int i = 0; i < NB; ++i) {
            f32x4 a0 = red[0][0][i][lane];
            f32x4 a1 = red[0][1][i][lane];
#pragma unroll
            for (int k = 1; k < RANK; ++k) {
                a0 += red[k][0][i][lane];
                a1 += red[k][1][i][lane];
            }
            float pn = __builtin_amdgcn_rsqf(np[i]);  // rsqrt(prod(1+x^2))
            a0 *= pn;
            a1 *= pn;
            f32x4* o = reinterpret_cast<f32x4*>(out + (rowbase + i * 64 + lane) * UNITS);
            o[0] = a0;
            o[1] = a1;
        }
    }
}

extern "C" void kernel_launch(void* const* d_in, const int* in_sizes, int n_in,
                              void* d_out, int out_size, void* d_ws, size_t ws_size,
                              hipStream_t stream) {
    const float* X = (const float*)d_in[0];
    const float* K = (const float*)d_in[1];
    float* out = (float*)d_out;
    int B = in_sizes[0] / F;  // 131072

    dim3 block(64, RANK);     // 640 threads = 10 waves
    dim3 grid(B / ROWS);      // 512 blocks
    hipLaunchKernelGGL(cp_based_kernel, grid, block, 0, stream, X, K, out, B);
}

// Round 5
// 31.624 us; speedup vs baseline: 3.1358x; 3.1358x over previous
//
#include <hip/hip_runtime.h>

// CP_Based: out[b,u] = rsqrt(prod_f (1+X^2)) * sum_r prod_f (k0[r,f,u] + X[b,f]*k1[r,f,u])
// X: [B,32] f32, kernel: [2,10,32,8] f32, out: [B,8] f32
//
// Established: scalar-pipe K streaming caps at ~1.4TB/s aggregate (R1/R3),
// VMEM K-broadcast 2.8x worse (R2), X re-read kills it (R4, FETCH 90MB).
// This round: K lives in VGPRs distributed over lanes (zero broadcast traffic),
// X staged once per block to LDS (coalesced) and read with 4-way-broadcast b128.
//
// Lane map: g=lane&7 (row in 8-row batch), up=(lane>>3)&3 (unit pair {up,up+4}),
// h=lane>>5 (f half). Wave y = rank y. Per-lane K = 2u x 16f x 2d = 64 VGPR.
// pk-f32 over natural f-pairs (zero dup movs). f-halves combined via shfl_xor 32.
// Rank reduction via col-XOR-swizzled LDS (conflict-minimal b128).

typedef float f32x2 __attribute__((ext_vector_type(2)));
typedef float f32x4 __attribute__((ext_vector_type(4)));

#define F 32
#define RANK 10
#define UNITS 8
#define RPB 128          // rows per block
#define NB8 (RPB / 8)    // 16 batches of 8 rows
#define XSTRIDE 36       // padded: banks (4g+16h) spread, max 2-way

__global__ __launch_bounds__(64 * RANK) void cp_based_kernel(
    const float* __restrict__ X,
    const float* __restrict__ K,
    float* __restrict__ out,
    int B)
{
    __shared__ float xs_[RPB][XSTRIDE];          // 18,432 B
    __shared__ float red_[RANK][RPB][UNITS];     // 40,960 B
    __shared__ float nrm_[RPB];                  //    512 B

    const int lane = threadIdx.x;
    const int y = __builtin_amdgcn_readfirstlane(threadIdx.y);   // rank
    const int tid = threadIdx.y * 64 + lane;
    const int g  = lane & 7;
    const int up = (lane >> 3) & 3;
    const int h  = lane >> 5;
    const long rowbase = (long)blockIdx.x * RPB;

    // ---- K preload into VGPRs (one-time, 64 b32 VMEM per lane)
    // kk{0,1}[uu][fp] = (K[d,y,fb+2fp,u], K[d,y,fb+2fp+1,u]); u=up+4uu, fb=16h
    f32x2 kk0[2][8], kk1[2][8];
    {
        const int fb = 16 * h;
#pragma unroll
        for (int uu = 0; uu < 2; ++uu) {
            const int u = up + 4 * uu;
#pragma unroll
            for (int fp = 0; fp < 8; ++fp) {
                const int f0 = fb + 2 * fp;
                kk0[uu][fp] = f32x2{K[((0 * RANK + y) * F + f0) * UNITS + u],
                                    K[((0 * RANK + y) * F + f0 + 1) * UNITS + u]};
                kk1[uu][fp] = f32x2{K[((1 * RANK + y) * F + f0) * UNITS + u],
                                    K[((1 * RANK + y) * F + f0 + 1) * UNITS + u]};
            }
        }
    }

    // ---- stage X tile once, coalesced (1024 f32x4 entries over 640 threads)
    for (int e = tid; e < RPB * 8; e += 64 * RANK) {
        const int row = e >> 3, jc = e & 7;
        f32x4 v = *reinterpret_cast<const f32x4*>(X + (rowbase + row) * F + jc * 4);
        *reinterpret_cast<f32x4*>(&xs_[row][jc * 4]) = v;
    }
    __syncthreads();

    for (int b8 = 0; b8 < NB8; ++b8) {
        const int row = b8 * 8 + g;

        f32x4 xq[4];
#pragma unroll
        for (int jc = 0; jc < 4; ++jc)
            xq[jc] = *reinterpret_cast<const f32x4*>(&xs_[row][16 * h + 4 * jc]);

        f32x2 p0 = {1.f, 1.f}, p1 = {1.f, 1.f}, npv = {1.f, 1.f};
#pragma unroll
        for (int jc = 0; jc < 4; ++jc) {
#pragma unroll
            for (int sub = 0; sub < 2; ++sub) {
                const int fp = jc * 2 + sub;
                f32x2 xp = {xq[jc][2 * sub], xq[jc][2 * sub + 1]};
                p0 *= xp * kk1[0][fp] + kk0[0][fp];   // pk_fma + pk_mul
                p1 *= xp * kk1[1][fp] + kk0[1][fp];
                if (y == 0) npv *= (xp * xp + f32x2{1.f, 1.f});
            }
        }
        // product over this lane's 16 f, per unit
        float pu0 = p0[0] * p0[1];
        float pu1 = p1[0] * p1[1];
        // combine the two f-halves (lane ^ 32 has the other 16 f)
        pu0 *= __shfl_xor(pu0, 32);
        pu1 *= __shfl_xor(pu1, 32);

        // write: lane h stores u = up + 4h; col XOR-swizzled by row parity so the
        // reduction's b128 reads are conflict-minimal
        const float pw = (h == 0) ? pu0 : pu1;
        const int col = (up + 4 * h) ^ (4 * (row & 1));
        red_[y][row][col] = pw;

        if (y == 0) {
            float npf = npv[0] * npv[1];
            npf *= __shfl_xor(npf, 32);
            if (lane == g) nrm_[row] = npf;   // up==0 && h==0 lanes
        }
    }
    __syncthreads();

    // ---- rank reduction + norm + coalesced store
    if (tid < RPB * 2) {
        const int row = tid >> 1, q = tid & 1;
        const int qp = 4 * (q ^ (row & 1));       // physical quad holding u=4q..4q+3
        f32x4 s = {0.f, 0.f, 0.f, 0.f};
#pragma unroll
        for (int k = 0; k < RANK; ++k)
            s += *reinterpret_cast<const f32x4*>(&red_[k][row][qp]);
        s *= __builtin_amdgcn_rsqf(nrm_[row]);
        *reinterpret_cast<f32x4*>(out + (rowbase + row) * UNITS + 4 * q) = s;
    }
}

extern "C" void kernel_launch(void* const* d_in, const int* in_sizes, int n_in,
                              void* d_out, int out_size, void* d_ws, size_t ws_size,
                              hipStream_t stream) {
    const float* X = (const float*)d_in[0];
    const float* K = (const float*)d_in[1];
    float* out = (float*)d_out;
    const int B = in_sizes[0] / F;   // 131072

    dim3 block(64, RANK);            // 640 threads
    dim3 grid(B / RPB);              // 1024 blocks
    hipLaunchKernelGGL(cp_based_kernel, grid, block, 0, stream, X, K, out, B);
}

// Round 6
// 31.498 us; speedup vs baseline: 3.1483x; 1.0040x over previous
//
#include <hip/hip_runtime.h>

// CP_Based: out[b,u] = rsqrt(prod_f (1+X^2)) * sum_r prod_f (k0[r,f,u] + X[b,f]*k1[r,f,u])
// X: [B,32] f32, kernel: [2,10,32,8] f32, out: [B,8] f32
//
// Model from R1-R5: the binding resource is per-CU scalar-load INSTRUCTION
// processing (~3.3 cyc/s_load: R1 and R3 both ran 20480 s_loads/CU in ~28-31us
// at 5x different TLP). VMEM K-broadcast is 2.8x worse (R2); LDS X-broadcast
// lands at the same ~31us via the LDS pipe (R5); X re-reads from HBM are 3.5x
// worse (R4). So: R1 structure (thread=row, K scalar, X per-thread registers),
// but K read as f32x4 quads -> compiler merges to s_load_dwordx8/x16 ->
// 4-8x fewer scalar instructions for the same 20KB/wave.

typedef float f32x2 __attribute__((ext_vector_type(2)));
typedef float f32x4 __attribute__((ext_vector_type(4)));

#define F 32
#define RANK 10
#define UNITS 8

__global__ __launch_bounds__(256) void cp_based_kernel(
    const float* __restrict__ X,
    const float* __restrict__ K,   // [2,10,32,8] flat
    float* __restrict__ out,
    int B)
{
    const int b = blockIdx.x * blockDim.x + threadIdx.x;
    if (b >= B) return;

    // ---- X row into registers (8 x dwordx4) + norm product
    const f32x4* xrow = reinterpret_cast<const f32x4*>(X + (size_t)b * F);
    float xv[F];
    float np = 1.0f;
#pragma unroll
    for (int i = 0; i < F / 4; ++i) {
        f32x4 v = xrow[i];
#pragma unroll
        for (int j = 0; j < 4; ++j) {
            float x = v[j];
            xv[i * 4 + j] = x;
            np *= __builtin_fmaf(x, x, 1.0f);   // prod(1+x^2); rsqrt once at end
        }
    }

    // K as quads at wave-uniform addresses -> SMEM path, mergeable to x8/x16
    const f32x4* K4 = reinterpret_cast<const f32x4*>(K);
    const int K1Q = RANK * F * UNITS / 4;   // quad offset of the d=1 block

    f32x2 acc0 = {0.f, 0.f}, acc1 = {0.f, 0.f}, acc2 = {0.f, 0.f}, acc3 = {0.f, 0.f};

    for (int r = 0; r < RANK; ++r) {
        f32x2 p0 = {1.f, 1.f}, p1 = {1.f, 1.f}, p2 = {1.f, 1.f}, p3 = {1.f, 1.f};
        const int rq = r * (F * UNITS / 4);   // quad index of k0[r,0,0]
#pragma unroll
        for (int f = 0; f < F; ++f) {
            // 8 consecutive floats per d -> two adjacent quads -> s_load_dwordx8;
            // f and f+1 are also consecutive -> x16 merge candidates.
            f32x4 k0a = K4[rq + 2 * f];
            f32x4 k0b = K4[rq + 2 * f + 1];
            f32x4 k1a = K4[K1Q + rq + 2 * f];
            f32x4 k1b = K4[K1Q + rq + 2 * f + 1];
            float x = xv[f];
            f32x2 xs = {x, x};
            p0 *= xs * f32x2{k1a[0], k1a[1]} + f32x2{k0a[0], k0a[1]};
            p1 *= xs * f32x2{k1a[2], k1a[3]} + f32x2{k0a[2], k0a[3]};
            p2 *= xs * f32x2{k1b[0], k1b[1]} + f32x2{k0b[0], k0b[1]};
            p3 *= xs * f32x2{k1b[2], k1b[3]} + f32x2{k0b[2], k0b[3]};
        }
        acc0 += p0; acc1 += p1; acc2 += p2; acc3 += p3;
    }

    const float pn = __builtin_amdgcn_rsqf(np);
    acc0 *= pn; acc1 *= pn; acc2 *= pn; acc3 *= pn;

    float* o = out + (size_t)b * UNITS;
    reinterpret_cast<f32x4*>(o)[0] = f32x4{acc0[0], acc0[1], acc1[0], acc1[1]};
    reinterpret_cast<f32x4*>(o)[1] = f32x4{acc2[0], acc2[1], acc3[0], acc3[1]};
}

extern "C" void kernel_launch(void* const* d_in, const int* in_sizes, int n_in,
                              void* d_out, int out_size, void* d_ws, size_t ws_size,
                              hipStream_t stream) {
    const float* X = (const float*)d_in[0];
    const float* K = (const float*)d_in[1];
    float* out = (float*)d_out;
    const int B = in_sizes[0] / F;   // 131072

    dim3 block(256);
    dim3 grid((B + 255) / 256);
    hipLaunchKernelGGL(cp_based_kernel, grid, block, 0, stream, X, K, out, B);
}